// Round 5
// baseline (145.799 us; speedup 1.0000x reference)
//
#include <hip/hip_runtime.h>

#define NUM_POSES 200

// clang-native vector types — __builtin_nontemporal_* rejects HIP_vector_type
typedef float        v4f __attribute__((ext_vector_type(4)));
typedef unsigned int v2u __attribute__((ext_vector_type(2)));

// ---- bf16 <-> f32 helpers (raw bits; RNE rounding on pack) ----
__device__ __forceinline__ float bf2f(unsigned int u16) {
    union { unsigned int u; float f; } v; v.u = u16 << 16; return v.f;
}
__device__ __forceinline__ unsigned int f2bf(float f) {
    union { float f; unsigned int u; } v; v.f = f;
    unsigned int r = v.u + 0x7FFFu + ((v.u >> 16) & 1u);
    return r >> 16;
}

// ---- Kernel 1: detect dtypes AND build the 200 pose matrices ----
// flags[0] = 1 if E is float32 (else bf16); flags[1] = 1 if n is int32 (else int64)
__global__ void prep_kernel(const unsigned short* __restrict__ E16,
                            const unsigned int* __restrict__ n32,
                            const void* __restrict__ Rv,
                            const void* __restrict__ Tv,
                            int* __restrict__ flags,
                            float* __restrict__ M) {
    __shared__ unsigned int sany;
    int t = threadIdx.x;
    if (t == 0) sany = 0u;
    __syncthreads();
    unsigned int local = 0u;
    // E probe: true-bf16 N(0,1) values all have |v| < ~10; f32 mantissa halves
    // read as bf16 give random exponents -> huge/NaN with high probability.
    for (int k = t; k < 4096; k += 256) {
        float a = fabsf(bf2f(E16[k]));
        if (!(a <= 1e6f)) local |= 1u;   // NaN also trips (NaN fails a<=1e6)
    }
    // n probe: int64 values in [0,200) have zero high words at odd int32 slots.
    if (n32[2 * t + 1] != 0u) local |= 2u;
    if (local) atomicOr(&sany, local);
    __syncthreads();
    unsigned int s = sany;
    if (t == 0) {
        flags[0] = (s & 1u) ? 1 : 0;
        flags[1] = (s & 2u) ? 1 : 0;
    }
    if (t >= NUM_POSES) return;
    int p = t;
    float wx, wy, wz, tx, ty, tz;
    if (s & 1u) {
        const float* R = (const float*)Rv; const float* T = (const float*)Tv;
        wx = R[3*p+0]; wy = R[3*p+1]; wz = R[3*p+2];
        tx = T[3*p+0]; ty = T[3*p+1]; tz = T[3*p+2];
    } else {
        const unsigned short* R = (const unsigned short*)Rv;
        const unsigned short* T = (const unsigned short*)Tv;
        wx = bf2f(R[3*p+0]); wy = bf2f(R[3*p+1]); wz = bf2f(R[3*p+2]);
        tx = bf2f(T[3*p+0]); ty = bf2f(T[3*p+1]); tz = bf2f(T[3*p+2]);
    }
    float t2 = wx*wx + wy*wy + wz*wz;
    float th = sqrtf(t2 + 1e-12f);
    float a  = sinf(th) / th;
    float b  = (1.0f - cosf(th)) / fmaxf(t2, 1e-12f);

    float* m = M + p * 16;
    m[0]  = 1.0f - b * (wy*wy + wz*wz);
    m[1]  = -a * wz + b * wx * wy;
    m[2]  =  a * wy + b * wx * wz;
    m[3]  = tx;
    m[4]  =  a * wz + b * wx * wy;
    m[5]  = 1.0f - b * (wx*wx + wz*wz);
    m[6]  = -a * wx + b * wy * wz;
    m[7]  = ty;
    m[8]  = -a * wy + b * wx * wz;
    m[9]  =  a * wx + b * wy * wz;
    m[10] = 1.0f - b * (wx*wx + wy*wy);
    m[11] = tz;
    m[12] = 0.0f; m[13] = 0.0f; m[14] = 0.0f; m[15] = 1.0f;
    // M row 3 = [0,0,0,1] lets apply_kernel treat ALL output rows uniformly:
    // out row 3 = 0*E0+0*E1+0*E2+1*E3 = E3 exactly (fp32, finite inputs).
}

// ---- Kernel 2: one OUTPUT ROW per thread, DIRECT loads (no cross-lane) ----
// Thread t -> element e=t>>2, row r=t&3. The four loads E[e][0..3] have the
// same unique-cache-line count per wave as one fully-coalesced load (16 lines
// per instruction, 4-lane same-address merging, lines fully consumed) but
// give 4-wide VMEM ILP and need no LDS/shuffle/lgkm waits.
__global__ __launch_bounds__(256) void apply_kernel(
        const void* __restrict__ nin,
        const void* __restrict__ Ein,
        const float4* __restrict__ M,
        void* __restrict__ outv,
        const int* __restrict__ flags,
        int N) {
    int t = blockIdx.x * blockDim.x + threadIdx.x;   // row index
    int e = t >> 2;                                  // element
    int r = t & 3;                                   // row within element
    if (e >= N) return;
    const int e_is_f32 = flags[0];
    const int n_is_i32 = flags[1];

    long long p = n_is_i32 ? (long long)((const int*)nin)[e]
                           : ((const long long*)nin)[e];
    float4 m = M[p * 4 + r];          // 12.8 KB table: L1-resident

    if (e_is_f32) {
        const v4f* Ee = (const v4f*)Ein + 4 * (size_t)e;
        v4f E0 = __builtin_nontemporal_load(Ee + 0);
        v4f E1 = __builtin_nontemporal_load(Ee + 1);
        v4f E2 = __builtin_nontemporal_load(Ee + 2);
        v4f E3 = __builtin_nontemporal_load(Ee + 3);
        v4f o;
        o.x = m.x*E0.x + m.y*E1.x + m.z*E2.x + m.w*E3.x;
        o.y = m.x*E0.y + m.y*E1.y + m.z*E2.y + m.w*E3.y;
        o.z = m.x*E0.z + m.y*E1.z + m.z*E2.z + m.w*E3.z;
        o.w = m.x*E0.w + m.y*E1.w + m.z*E2.w + m.w*E3.w;
        __builtin_nontemporal_store(o, (v4f*)outv + t);
    } else {
        const v2u* Ee = (const v2u*)Ein + 4 * (size_t)e;
        v2u w0 = __builtin_nontemporal_load(Ee + 0);
        v2u w1 = __builtin_nontemporal_load(Ee + 1);
        v2u w2 = __builtin_nontemporal_load(Ee + 2);
        v2u w3 = __builtin_nontemporal_load(Ee + 3);
        float E0x = bf2f(w0.x & 0xFFFFu), E0y = bf2f(w0.x >> 16), E0z = bf2f(w0.y & 0xFFFFu), E0w = bf2f(w0.y >> 16);
        float E1x = bf2f(w1.x & 0xFFFFu), E1y = bf2f(w1.x >> 16), E1z = bf2f(w1.y & 0xFFFFu), E1w = bf2f(w1.y >> 16);
        float E2x = bf2f(w2.x & 0xFFFFu), E2y = bf2f(w2.x >> 16), E2z = bf2f(w2.y & 0xFFFFu), E2w = bf2f(w2.y >> 16);
        float E3x = bf2f(w3.x & 0xFFFFu), E3y = bf2f(w3.x >> 16), E3z = bf2f(w3.y & 0xFFFFu), E3w = bf2f(w3.y >> 16);
        float ox = m.x*E0x + m.y*E1x + m.z*E2x + m.w*E3x;
        float oy = m.x*E0y + m.y*E1y + m.z*E2y + m.w*E3y;
        float oz = m.x*E0z + m.y*E1z + m.z*E2z + m.w*E3z;
        float ow = m.x*E0w + m.y*E1w + m.z*E2w + m.w*E3w;
        v2u pk;
        pk.x = f2bf(ox) | (f2bf(oy) << 16);
        pk.y = f2bf(oz) | (f2bf(ow) << 16);
        __builtin_nontemporal_store(pk, (v2u*)outv + t);
    }
}

extern "C" void kernel_launch(void* const* d_in, const int* in_sizes, int n_in,
                              void* d_out, int out_size, void* d_ws, size_t ws_size,
                              hipStream_t stream) {
    const void* n = d_in[0];
    const void* E = d_in[1];
    const void* R = d_in[2];
    const void* T = d_in[3];
    int*    flags = (int*)d_ws;                    // 2 ints
    float*      M = (float*)((char*)d_ws + 256);   // 200*16 fp32, 16B-aligned
    const int   N = in_sizes[0];

    prep_kernel<<<1, 256, 0, stream>>>((const unsigned short*)E,
                                       (const unsigned int*)n, R, T, flags, M);
    const int rows = N * 4;
    apply_kernel<<<(rows + 255) / 256, 256, 0, stream>>>(
        n, E, (const float4*)M, d_out, flags, N);
}

// Round 6
// 134.509 us; speedup vs baseline: 1.0839x; 1.0839x over previous
//
#include <hip/hip_runtime.h>

#define NUM_POSES 200

typedef float        v4f __attribute__((ext_vector_type(4)));
typedef unsigned int v2u __attribute__((ext_vector_type(2)));

// ---- bf16 <-> f32 helpers ----
__device__ __forceinline__ float bf2f(unsigned int u16) {
    union { unsigned int u; float f; } v; v.u = u16 << 16; return v.f;
}
__device__ __forceinline__ unsigned int f2bf(float f) {
    union { float f; unsigned int u; } v; v.f = f;
    unsigned int r = v.u + 0x7FFFu + ((v.u >> 16) & 1u);
    return r >> 16;
}

// ---- DPP quad rotation: lane r of each 4-lane quad gets lane (r+K)&3's value.
// Pure VALU (v_mov_b32_dpp) — no LDS pipe, no lgkmcnt.
template <int CTRL>
__device__ __forceinline__ float rotf(float v) {
    int i = __builtin_bit_cast(int, v);
    i = __builtin_amdgcn_mov_dpp(i, CTRL, 0xF, 0xF, true);
    return __builtin_bit_cast(float, i);
}
template <int CTRL>
__device__ __forceinline__ v4f rot4(v4f v) {
    v4f r;
    r.x = rotf<CTRL>(v.x); r.y = rotf<CTRL>(v.y);
    r.z = rotf<CTRL>(v.z); r.w = rotf<CTRL>(v.w);
    return r;
}
#define ROT1 0x39   // perm [1,2,3,0]
#define ROT2 0x4E   // perm [2,3,0,1]
#define ROT3 0x93   // perm [3,0,1,2]

// ---- Kernel 1: detect dtypes AND build ROTATED pose matrices ----
// Mrot[p*16 + r*4 + k] = m[r][(r+k)&3]  -> runtime FMA needs no selects.
// flags[0]=1 if E is f32 (else bf16); flags[1]=1 if n is int32 (else int64)
__global__ void prep_kernel(const unsigned short* __restrict__ E16,
                            const unsigned int* __restrict__ n32,
                            const void* __restrict__ Rv,
                            const void* __restrict__ Tv,
                            int* __restrict__ flags,
                            float* __restrict__ M) {
    __shared__ unsigned int sany;
    int t = threadIdx.x;
    if (t == 0) sany = 0u;
    __syncthreads();
    unsigned int local = 0u;
    for (int k = t; k < 4096; k += 256) {
        float a = fabsf(bf2f(E16[k]));
        if (!(a <= 1e6f)) local |= 1u;   // f32-as-bf16 -> huge/NaN trips this
    }
    if (n32[2 * t + 1] != 0u) local |= 2u;  // int64 high words are 0 for p<200
    if (local) atomicOr(&sany, local);
    __syncthreads();
    unsigned int s = sany;
    if (t == 0) { flags[0] = (s & 1u) ? 1 : 0; flags[1] = (s & 2u) ? 1 : 0; }
    if (t >= NUM_POSES) return;
    int p = t;
    float wx, wy, wz, tx, ty, tz;
    if (s & 1u) {
        const float* R = (const float*)Rv; const float* T = (const float*)Tv;
        wx = R[3*p+0]; wy = R[3*p+1]; wz = R[3*p+2];
        tx = T[3*p+0]; ty = T[3*p+1]; tz = T[3*p+2];
    } else {
        const unsigned short* R = (const unsigned short*)Rv;
        const unsigned short* T = (const unsigned short*)Tv;
        wx = bf2f(R[3*p+0]); wy = bf2f(R[3*p+1]); wz = bf2f(R[3*p+2]);
        tx = bf2f(T[3*p+0]); ty = bf2f(T[3*p+1]); tz = bf2f(T[3*p+2]);
    }
    float t2 = wx*wx + wy*wy + wz*wz;
    float th = sqrtf(t2 + 1e-12f);
    float a  = sinf(th) / th;
    float b  = (1.0f - cosf(th)) / fmaxf(t2, 1e-12f);

    float mm[4][4];
    mm[0][0] = 1.0f - b * (wy*wy + wz*wz);
    mm[0][1] = -a * wz + b * wx * wy;
    mm[0][2] =  a * wy + b * wx * wz;
    mm[0][3] = tx;
    mm[1][0] =  a * wz + b * wx * wy;
    mm[1][1] = 1.0f - b * (wx*wx + wz*wz);
    mm[1][2] = -a * wx + b * wy * wz;
    mm[1][3] = ty;
    mm[2][0] = -a * wy + b * wx * wz;
    mm[2][1] =  a * wx + b * wy * wz;
    mm[2][2] = 1.0f - b * (wx*wx + wy*wy);
    mm[2][3] = tz;
    mm[3][0] = 0.0f; mm[3][1] = 0.0f; mm[3][2] = 0.0f; mm[3][3] = 1.0f;
    // row 3 rotated = (1,0,0,0): out row 3 = 1*E3 exactly (bit passthrough).
    float* mo = M + p * 16;
    #pragma unroll
    for (int r = 0; r < 4; ++r)
        #pragma unroll
        for (int k = 0; k < 4; ++k)
            mo[r*4 + k] = mm[r][(r + k) & 3];
}

// ---- Kernel 2: one row/thread, ONE coalesced load + ONE coalesced store,
// row exchange via DPP quad-perm. Two rows per thread for MLP. ----
__global__ __launch_bounds__(256) void apply_kernel(
        const void* __restrict__ nin,
        const void* __restrict__ Ein,
        const float4* __restrict__ Mrot,
        void* __restrict__ outv,
        const int* __restrict__ flags,
        int N) {
    const int TOT  = gridDim.x * blockDim.x;         // multiple of 256
    const int rows = N * 4;
    int t0 = blockIdx.x * blockDim.x + threadIdx.x;  // first row
    int t1 = t0 + TOT;                               // second row (quad-aligned)
    const int e_is_f32 = flags[0];
    const int n_is_i32 = flags[1];

    #pragma unroll
    for (int u = 0; u < 2; ++u) {
        int t = u ? t1 : t0;
        if (t >= rows) return;
        int e = t >> 2;
        int r = t & 3;
        long long p = n_is_i32 ? (long long)((const int*)nin)[e]
                               : ((const long long*)nin)[e];
        float4 c = Mrot[p * 4 + r];   // pre-rotated coeffs, 12.8 KB L1-resident

        if (e_is_f32) {
            v4f self = __builtin_nontemporal_load((const v4f*)Ein + t);
            v4f e1 = rot4<ROT1>(self);
            v4f e2 = rot4<ROT2>(self);
            v4f e3 = rot4<ROT3>(self);
            v4f o = c.x * self + c.y * e1 + c.z * e2 + c.w * e3;
            __builtin_nontemporal_store(o, (v4f*)outv + t);
        } else {
            v2u raw = __builtin_nontemporal_load((const v2u*)Ein + t);
            v4f self;
            self.x = bf2f(raw.x & 0xFFFFu); self.y = bf2f(raw.x >> 16);
            self.z = bf2f(raw.y & 0xFFFFu); self.w = bf2f(raw.y >> 16);
            v4f e1 = rot4<ROT1>(self);
            v4f e2 = rot4<ROT2>(self);
            v4f e3 = rot4<ROT3>(self);
            v4f o = c.x * self + c.y * e1 + c.z * e2 + c.w * e3;
            v2u pk;
            pk.x = f2bf(o.x) | (f2bf(o.y) << 16);
            pk.y = f2bf(o.z) | (f2bf(o.w) << 16);
            __builtin_nontemporal_store(pk, (v2u*)outv + t);
        }
    }
}

extern "C" void kernel_launch(void* const* d_in, const int* in_sizes, int n_in,
                              void* d_out, int out_size, void* d_ws, size_t ws_size,
                              hipStream_t stream) {
    const void* n = d_in[0];
    const void* E = d_in[1];
    const void* R = d_in[2];
    const void* T = d_in[3];
    int*    flags = (int*)d_ws;
    float*      M = (float*)((char*)d_ws + 256);   // 200*16 fp32 rotated table
    const int   N = in_sizes[0];

    prep_kernel<<<1, 256, 0, stream>>>((const unsigned short*)E,
                                       (const unsigned int*)n, R, T, flags, M);
    const int rows   = N * 4;
    const int blocks = (rows + 511) / 512;           // 2 rows per thread
    apply_kernel<<<blocks, 256, 0, stream>>>(
        n, E, (const float4*)M, d_out, flags, N);
}

// Round 7
// 124.239 us; speedup vs baseline: 1.1735x; 1.0827x over previous
//
#include <hip/hip_runtime.h>

#define NUM_POSES 200

typedef float        v4f __attribute__((ext_vector_type(4)));
typedef unsigned int v2u __attribute__((ext_vector_type(2)));

// ---- bf16 <-> f32 helpers ----
__device__ __forceinline__ float bf2f(unsigned int u16) {
    union { unsigned int u; float f; } v; v.u = u16 << 16; return v.f;
}
__device__ __forceinline__ unsigned int f2bf(float f) {
    union { float f; unsigned int u; } v; v.f = f;
    unsigned int r = v.u + 0x7FFFu + ((v.u >> 16) & 1u);
    return r >> 16;
}

// ---- DPP quad rotation (verified in R6): lane r gets lane (r+K)&3 ----
template <int CTRL>
__device__ __forceinline__ float rotf(float v) {
    int i = __builtin_bit_cast(int, v);
    i = __builtin_amdgcn_mov_dpp(i, CTRL, 0xF, 0xF, true);
    return __builtin_bit_cast(float, i);
}
template <int CTRL>
__device__ __forceinline__ v4f rot4(v4f v) {
    v4f r;
    r.x = rotf<CTRL>(v.x); r.y = rotf<CTRL>(v.y);
    r.z = rotf<CTRL>(v.z); r.w = rotf<CTRL>(v.w);
    return r;
}
#define ROT1 0x39   // quad_perm [1,2,3,0]
#define ROT2 0x4E   // quad_perm [2,3,0,1]
#define ROT3 0x93   // quad_perm [3,0,1,2]

// ---- ONE fused kernel: per-block detect + Rodrigues-into-LDS + apply ----
// Detect (wave 0, 64 L2-hot words each of E and n) and the 200-pose rotated
// coefficient table are recomputed per block: removes the serial 1-block prep
// dispatch and takes the M-gather off the L1 (shared with streaming E loads).
__global__ __launch_bounds__(256) void fused_kernel(
        const void* __restrict__ nin,
        const void* __restrict__ Ein,
        const void* __restrict__ Rv,
        const void* __restrict__ Tv,
        void* __restrict__ outv,
        int N) {
    __shared__ v4f Ml[NUM_POSES * 4];   // Ml[p*4+r].k = m[r][(r+k)&3]
    __shared__ int sflags;
    const int tid = threadIdx.x;

    // --- detect dtypes (wave 0 only; data L2/L3-hot after first blocks) ---
    if (tid < 64) {
        unsigned int dw = ((const unsigned int*)Ein)[tid];
        // low 16 bits of an f32 are mantissa bits -> as bf16: random exponent
        // -> huge/NaN w.p. ~0.42/word; true-bf16 N(0,1) values stay < ~10.
        bool ef32 = !(fabsf(bf2f(dw & 0xFFFFu)) <= 1e6f);
        // int64 n in [0,200): odd int32 words (high halves) are all zero.
        bool ni32 = ((const unsigned int*)nin)[2 * tid + 1] != 0u;
        unsigned long long b1 = __ballot(ef32);
        unsigned long long b2 = __ballot(ni32);
        if (tid == 0) sflags = (b1 ? 1 : 0) | (b2 ? 2 : 0);
    }
    __syncthreads();
    const int s = sflags;

    // --- Rodrigues for all 200 poses, rotated layout, into LDS ---
    if (tid < NUM_POSES) {
        int p = tid;
        float wx, wy, wz, tx, ty, tz;
        if (s & 1) {
            const float* R = (const float*)Rv; const float* T = (const float*)Tv;
            wx = R[3*p+0]; wy = R[3*p+1]; wz = R[3*p+2];
            tx = T[3*p+0]; ty = T[3*p+1]; tz = T[3*p+2];
        } else {
            const unsigned short* R = (const unsigned short*)Rv;
            const unsigned short* T = (const unsigned short*)Tv;
            wx = bf2f(R[3*p+0]); wy = bf2f(R[3*p+1]); wz = bf2f(R[3*p+2]);
            tx = bf2f(T[3*p+0]); ty = bf2f(T[3*p+1]); tz = bf2f(T[3*p+2]);
        }
        float t2 = wx*wx + wy*wy + wz*wz;
        float th = sqrtf(t2 + 1e-12f);
        float a  = sinf(th) / th;
        float b  = (1.0f - cosf(th)) / fmaxf(t2, 1e-12f);

        float mm[4][4];
        mm[0][0] = 1.0f - b * (wy*wy + wz*wz);
        mm[0][1] = -a * wz + b * wx * wy;
        mm[0][2] =  a * wy + b * wx * wz;
        mm[0][3] = tx;
        mm[1][0] =  a * wz + b * wx * wy;
        mm[1][1] = 1.0f - b * (wx*wx + wz*wz);
        mm[1][2] = -a * wx + b * wy * wz;
        mm[1][3] = ty;
        mm[2][0] = -a * wy + b * wx * wz;
        mm[2][1] =  a * wx + b * wy * wz;
        mm[2][2] = 1.0f - b * (wx*wx + wy*wy);
        mm[2][3] = tz;
        mm[3][0] = 0.0f; mm[3][1] = 0.0f; mm[3][2] = 0.0f; mm[3][3] = 1.0f;
        // rotated row 3 = (1,0,0,0): out row 3 = 1*E3 exactly (passthrough).
        #pragma unroll
        for (int r = 0; r < 4; ++r) {
            v4f c;
            c.x = mm[r][(r + 0) & 3];
            c.y = mm[r][(r + 1) & 3];
            c.z = mm[r][(r + 2) & 3];
            c.w = mm[r][(r + 3) & 3];
            Ml[p * 4 + r] = c;
        }
    }
    __syncthreads();

    // --- main: 4 rows/thread, loads hoisted for MLP, coalesced, DPP rows ---
    const int rows = N * 4;                       // rows % 4 == 0 -> quads uniform
    const int TOT  = gridDim.x * blockDim.x;
    const int t0   = blockIdx.x * blockDim.x + tid;
    const bool ef32 = (s & 1) != 0;
    const bool ni32 = (s & 2) != 0;

    int t[4];
    #pragma unroll
    for (int k = 0; k < 4; ++k) t[k] = t0 + k * TOT;

    if (ef32) {
        v4f self[4], c[4];
        #pragma unroll
        for (int k = 0; k < 4; ++k)
            if (t[k] < rows) self[k] = ((const v4f*)Ein)[t[k]];
        #pragma unroll
        for (int k = 0; k < 4; ++k)
            if (t[k] < rows) {
                int e = t[k] >> 2, r = t[k] & 3;
                long long p = ni32 ? (long long)((const int*)nin)[e]
                                   : ((const long long*)nin)[e];
                c[k] = Ml[p * 4 + r];
            }
        #pragma unroll
        for (int k = 0; k < 4; ++k)
            if (t[k] < rows) {
                v4f o = c[k].x * self[k]
                      + c[k].y * rot4<ROT1>(self[k])
                      + c[k].z * rot4<ROT2>(self[k])
                      + c[k].w * rot4<ROT3>(self[k]);
                __builtin_nontemporal_store(o, (v4f*)outv + t[k]);
            }
    } else {
        v2u raw[4]; v4f c[4];
        #pragma unroll
        for (int k = 0; k < 4; ++k)
            if (t[k] < rows) raw[k] = ((const v2u*)Ein)[t[k]];
        #pragma unroll
        for (int k = 0; k < 4; ++k)
            if (t[k] < rows) {
                int e = t[k] >> 2, r = t[k] & 3;
                long long p = ni32 ? (long long)((const int*)nin)[e]
                                   : ((const long long*)nin)[e];
                c[k] = Ml[p * 4 + r];
            }
        #pragma unroll
        for (int k = 0; k < 4; ++k)
            if (t[k] < rows) {
                v4f self;
                self.x = bf2f(raw[k].x & 0xFFFFu); self.y = bf2f(raw[k].x >> 16);
                self.z = bf2f(raw[k].y & 0xFFFFu); self.w = bf2f(raw[k].y >> 16);
                v4f o = c[k].x * self
                      + c[k].y * rot4<ROT1>(self)
                      + c[k].z * rot4<ROT2>(self)
                      + c[k].w * rot4<ROT3>(self);
                v2u pk;
                pk.x = f2bf(o.x) | (f2bf(o.y) << 16);
                pk.y = f2bf(o.z) | (f2bf(o.w) << 16);
                __builtin_nontemporal_store(pk, (v2u*)outv + t[k]);
            }
    }
}

extern "C" void kernel_launch(void* const* d_in, const int* in_sizes, int n_in,
                              void* d_out, int out_size, void* d_ws, size_t ws_size,
                              hipStream_t stream) {
    const void* n = d_in[0];
    const void* E = d_in[1];
    const void* R = d_in[2];
    const void* T = d_in[3];
    const int   N = in_sizes[0];

    const int rows    = N * 4;
    const int threads = (rows + 3) / 4;            // 4 rows per thread
    const int blocks  = (threads + 255) / 256;
    fused_kernel<<<blocks, 256, 0, stream>>>(n, E, R, T, d_out, N);
}